// Round 2
// baseline (6011.504 us; speedup 1.0000x reference)
//
#include <hip/hip_runtime.h>

#define B_    4
#define CIN_  64
#define LEN_  1024
#define DIM_  1024
#define NH_   16
#define DH_   64
#define SLEN_ 512
#define HID_  2730
#define GLD_  2736   // K padded to multiple of 16; zero-filled tail

__device__ __forceinline__ float wave_sum(float v) {
#pragma unroll
  for (int off = 32; off; off >>= 1) v += __shfl_xor(v, off);
  return v;
}
__device__ __forceinline__ float wave_max(float v) {
#pragma unroll
  for (int off = 32; off; off >>= 1) v = fmaxf(v, __shfl_xor(v, off));
  return v;
}

// ---------------- group-norm stats (two-stage, deterministic) ----------------
extern "C" __global__ __launch_bounds__(256)
void k_partial_stats(const float* __restrict__ x, float2* __restrict__ part, int perBatch) {
  int b = blockIdx.y, chunk = blockIdx.x;
  int chunkElems = perBatch >> 6;  // 64 chunks per batch
  const float4* p = (const float4*)(x + (size_t)b * perBatch + (size_t)chunk * chunkElems);
  int n4 = chunkElems >> 2;
  float s = 0.f, sq = 0.f;
  for (int i = threadIdx.x; i < n4; i += 256) {
    float4 v = p[i];
    s += v.x + v.y + v.z + v.w;
    sq += v.x * v.x + v.y * v.y + v.z * v.z + v.w * v.w;
  }
  s = wave_sum(s); sq = wave_sum(sq);
  __shared__ float red[8];
  int w = threadIdx.x >> 6;
  if ((threadIdx.x & 63) == 0) { red[w] = s; red[4 + w] = sq; }
  __syncthreads();
  if (threadIdx.x == 0) {
    part[b * 64 + chunk] = make_float2(red[0] + red[1] + red[2] + red[3],
                                       red[4] + red[5] + red[6] + red[7]);
  }
}

extern "C" __global__ __launch_bounds__(64)
void k_finalize_stats(const float2* __restrict__ part, float2* __restrict__ mr,
                      float invN, float eps) {
  int b = blockIdx.x;
  float2 v = part[b * 64 + threadIdx.x];
  float s = wave_sum(v.x), sq = wave_sum(v.y);
  if (threadIdx.x == 0) {
    float mean = s * invN;
    float var = sq * invN - mean * mean;
    mr[b] = make_float2(mean, rsqrtf(var + eps));
  }
}

// ---------------- groupnorm-apply + silu (elementwise) ----------------
extern "C" __global__ __launch_bounds__(256)
void k_gn_silu(const float* __restrict__ x, const float2* __restrict__ mr,
               const float* __restrict__ w, const float* __restrict__ bias,
               float* __restrict__ y, int cshift, int total4) {
  int idx = blockIdx.x * 256 + threadIdx.x;
  if (idx >= total4) return;
  int cl = idx >> 8;                       // (idx*4)/1024 = row index (b*C + c)
  int c = cl & ((1 << cshift) - 1);
  int b = cl >> cshift;
  float2 m = mr[b];
  float wc = w[c] * m.y;
  float bc = bias[c] - m.x * m.y * w[c];
  float4 v = ((const float4*)x)[idx];
  float4 o;
  float t;
  t = v.x * wc + bc; o.x = t / (1.f + __expf(-t));
  t = v.y * wc + bc; o.y = t / (1.f + __expf(-t));
  t = v.z * wc + bc; o.z = t / (1.f + __expf(-t));
  t = v.w * wc + bc; o.w = t / (1.f + __expf(-t));
  ((float4*)y)[idx] = o;
}

// ---------------- conv1d k=3 pad=1 (tiled) ----------------
extern "C" __global__ __launch_bounds__(256)
void k_conv1d_k3(const float* __restrict__ in, const float* __restrict__ w,
                 const float* __restrict__ bias, float* __restrict__ out,
                 int Cin, int Cout) {
  __shared__ float in_lds[16][66];
  __shared__ float w_lds[64][49];
  int b = blockIdx.z;
  int d0 = blockIdx.y * 64;
  int l0 = blockIdx.x * 64;
  int tid = threadIdx.x;
  int tc = tid & 15, tr = tid >> 4;
  float acc[4][4] = {{0.f}};
  for (int c0 = 0; c0 < Cin; c0 += 16) {
    __syncthreads();
    for (int idx = tid; idx < 16 * 66; idx += 256) {
      int cc = idx / 66, ll = idx % 66;
      int gl = l0 + ll - 1;
      float v = 0.f;
      if (gl >= 0 && gl < LEN_) v = in[((size_t)b * Cin + (c0 + cc)) * LEN_ + gl];
      in_lds[cc][ll] = v;
    }
    for (int idx = tid; idx < 64 * 48; idx += 256) {
      int dd = idx / 48, r = idx % 48;
      w_lds[dd][r] = w[((size_t)(d0 + dd) * Cin + c0) * 3 + r];
    }
    __syncthreads();
#pragma unroll 4
    for (int cc = 0; cc < 16; ++cc) {
      float iv[6];
#pragma unroll
      for (int u = 0; u < 6; ++u) iv[u] = in_lds[cc][tc * 4 + u];
      float wv[4][3];
#pragma unroll
      for (int i = 0; i < 4; ++i)
#pragma unroll
        for (int k = 0; k < 3; ++k) wv[i][k] = w_lds[tr * 4 + i][cc * 3 + k];
#pragma unroll
      for (int i = 0; i < 4; ++i)
#pragma unroll
        for (int j = 0; j < 4; ++j)
#pragma unroll
          for (int k = 0; k < 3; ++k)
            acc[i][j] = fmaf(wv[i][k], iv[j + k], acc[i][j]);
    }
  }
#pragma unroll
  for (int i = 0; i < 4; ++i) {
    int d = d0 + tr * 4 + i;
    float bs = bias[d];
    float4 res = make_float4(acc[i][0] + bs, acc[i][1] + bs, acc[i][2] + bs, acc[i][3] + bs);
    *(float4*)&out[((size_t)b * Cout + d) * LEN_ + l0 + tc * 4] = res;
  }
}

// ---------------- skip-conv (k=1) + add + transpose -> t[b,l,d] ----------------
extern "C" __global__ __launch_bounds__(256)
void k_add_skip(const float* __restrict__ x, const float* __restrict__ sw,
                const float* __restrict__ sb, const float* __restrict__ h2,
                float* __restrict__ t) {
  __shared__ float x_lds[64][65];   // [c][l_local]
  __shared__ float w_lds[64][65];   // [d_local][c]
  __shared__ float h_lds[64][68];   // [l_local][d_local]
  int b = blockIdx.z;
  int d0 = blockIdx.y * 64;
  int l0 = blockIdx.x * 64;
  int tid = threadIdx.x;
  int tn = tid & 15, tm = tid >> 4;
  for (int idx = tid; idx < 4096; idx += 256) {
    int r = idx >> 6, q = idx & 63;
    x_lds[r][q] = x[((size_t)b * CIN_ + r) * LEN_ + l0 + q];
    w_lds[r][q] = sw[(size_t)(d0 + r) * CIN_ + q];
    h_lds[q][r] = h2[((size_t)b * DIM_ + d0 + r) * LEN_ + l0 + q];
  }
  __syncthreads();
  float acc[4][4] = {{0.f}};
#pragma unroll 8
  for (int c = 0; c < 64; ++c) {
    float xv[4], wv[4];
#pragma unroll
    for (int il = 0; il < 4; ++il) xv[il] = x_lds[c][tm * 4 + il];
#pragma unroll
    for (int jd = 0; jd < 4; ++jd) wv[jd] = w_lds[tn * 4 + jd][c];
#pragma unroll
    for (int il = 0; il < 4; ++il)
#pragma unroll
      for (int jd = 0; jd < 4; ++jd)
        acc[il][jd] = fmaf(xv[il], wv[jd], acc[il][jd]);
  }
  float4 bb = *(const float4*)&sb[d0 + tn * 4];
#pragma unroll
  for (int il = 0; il < 4; ++il) {
    int l = l0 + tm * 4 + il;
    float4 hv = *(const float4*)&h_lds[tm * 4 + il][tn * 4];
    float4 res = make_float4(acc[il][0] + hv.x + bb.x, acc[il][1] + hv.y + bb.y,
                             acc[il][2] + hv.z + bb.z, acc[il][3] + hv.w + bb.w);
    *(float4*)&t[((size_t)(b * LEN_ + l)) * DIM_ + d0 + tn * 4] = res;
  }
}

// ---------------- rmsnorm over last dim (1024) ----------------
extern "C" __global__ __launch_bounds__(256)
void k_rmsnorm(const float* __restrict__ x, const float* __restrict__ w,
               float* __restrict__ y) {
  size_t row = blockIdx.x;
  const float4* xr = (const float4*)(x + row * DIM_);
  float4 v = xr[threadIdx.x];
  float ss = v.x * v.x + v.y * v.y + v.z * v.z + v.w * v.w;
  ss = wave_sum(ss);
  __shared__ float red[4];
  if ((threadIdx.x & 63) == 0) red[threadIdx.x >> 6] = ss;
  __syncthreads();
  float tot = red[0] + red[1] + red[2] + red[3];
  float rs = rsqrtf(tot * (1.f / DIM_) + 1e-6f);
  float4 wv = ((const float4*)w)[threadIdx.x];
  float4 o = make_float4(v.x * rs * wv.x, v.y * rs * wv.y, v.z * rs * wv.z, v.w * rs * wv.w);
  ((float4*)(y + row * DIM_))[threadIdx.x] = o;
}

// ---------------- pad-repack w3_w [1024][2730] -> [1024][2736] (zero tail) ----
extern "C" __global__ __launch_bounds__(256)
void k_padcopy_w3(const float* __restrict__ src, float* __restrict__ dst) {
  int idx = blockIdx.x * 256 + threadIdx.x;   // over 1024*2736, exact grid
  int n = idx / GLD_;
  int k = idx - n * GLD_;
  dst[idx] = (k < HID_) ? src[(size_t)n * HID_ + k] : 0.f;
}

// ------- generic fp32 GEMM: C[M,N] = A[M,K] * W[N,K]^T (+add)(+bias) --------
// REQUIRES: M%128==0 (grid.y=M/128), N%128==0 (grid.x=N/128), K%16==0,
//           lda%4==0, ldw%4==0. No bounds checks.
extern "C" __global__ __launch_bounds__(256)
void k_sgemm(const float* __restrict__ A, int lda,
             const float* __restrict__ W, int ldw,
             const float* __restrict__ addsrc, const float* __restrict__ bias,
             float* __restrict__ C, int ldc,
             int K) {
  __shared__ float a_lds[16][132];
  __shared__ float w_lds[16][132];
  int n0 = blockIdx.x * 128;
  int m0 = blockIdx.y * 128;
  int tid = threadIdx.x;
  int tn = tid & 15, tm = tid >> 4;
  float acc[8][8] = {{0.f}};
  for (int k0 = 0; k0 < K; k0 += 16) {
    __syncthreads();
#pragma unroll
    for (int q = 0; q < 2; ++q) {
      int s = tid * 2 + q;                 // 0..511
      int mm = s >> 2, kk = (s & 3) << 2;
      float4 av = *(const float4*)&A[(size_t)(m0 + mm) * lda + k0 + kk];
      a_lds[kk + 0][mm] = av.x; a_lds[kk + 1][mm] = av.y;
      a_lds[kk + 2][mm] = av.z; a_lds[kk + 3][mm] = av.w;
      float4 wv = *(const float4*)&W[(size_t)(n0 + mm) * ldw + k0 + kk];
      w_lds[kk + 0][mm] = wv.x; w_lds[kk + 1][mm] = wv.y;
      w_lds[kk + 2][mm] = wv.z; w_lds[kk + 3][mm] = wv.w;
    }
    __syncthreads();
#pragma unroll
    for (int kk = 0; kk < 16; ++kk) {
      float4 a0 = *(const float4*)&a_lds[kk][tm * 8];
      float4 a1 = *(const float4*)&a_lds[kk][tm * 8 + 4];
      float4 w0 = *(const float4*)&w_lds[kk][tn * 8];
      float4 w1 = *(const float4*)&w_lds[kk][tn * 8 + 4];
      float av[8] = {a0.x, a0.y, a0.z, a0.w, a1.x, a1.y, a1.z, a1.w};
      float wv[8] = {w0.x, w0.y, w0.z, w0.w, w1.x, w1.y, w1.z, w1.w};
#pragma unroll
      for (int i = 0; i < 8; ++i)
#pragma unroll
        for (int j = 0; j < 8; ++j)
          acc[i][j] = fmaf(av[i], wv[j], acc[i][j]);
    }
  }
#pragma unroll
  for (int i = 0; i < 8; ++i) {
    int m = m0 + tm * 8 + i;
    int n = n0 + tn * 8;
    size_t off = (size_t)m * ldc + n;
    float4 r0 = make_float4(acc[i][0], acc[i][1], acc[i][2], acc[i][3]);
    float4 r1 = make_float4(acc[i][4], acc[i][5], acc[i][6], acc[i][7]);
    if (bias) {
      float4 b0 = *(const float4*)&bias[n];
      float4 b1 = *(const float4*)&bias[n + 4];
      r0.x += b0.x; r0.y += b0.y; r0.z += b0.z; r0.w += b0.w;
      r1.x += b1.x; r1.y += b1.y; r1.z += b1.z; r1.w += b1.w;
    }
    if (addsrc) {
      float4 s0 = *(const float4*)&addsrc[off];
      float4 s1 = *(const float4*)&addsrc[off + 4];
      r0.x += s0.x; r0.y += s0.y; r0.z += s0.z; r0.w += s0.w;
      r1.x += s1.x; r1.y += s1.y; r1.z += s1.z; r1.w += s1.w;
    }
    *(float4*)&C[off] = r0;
    *(float4*)&C[off + 4] = r1;
  }
}

// ---------------- fused GLU GEMM: g = silu(A*W1^T) * (A*W2^T) ----------------
// writes zero into pad columns [HID_, GLD_)
extern "C" __global__ __launch_bounds__(256)
void k_glu_gemm(const float* __restrict__ A, const float* __restrict__ W,
                float* __restrict__ G) {
  __shared__ float a_lds[16][132];
  __shared__ float w1_lds[16][68];
  __shared__ float w2_lds[16][68];
  int n0 = blockIdx.x * 64;
  int m0 = blockIdx.y * 128;
  int tid = threadIdx.x;
  int tn = tid & 15, tm = tid >> 4;
  float acc1[8][4] = {{0.f}}, acc2[8][4] = {{0.f}};
  for (int k0 = 0; k0 < DIM_; k0 += 16) {
    __syncthreads();
#pragma unroll
    for (int q = 0; q < 2; ++q) {
      int s = tid * 2 + q;
      int mm = s >> 2, kk = (s & 3) << 2;
      float4 av = *(const float4*)&A[(size_t)(m0 + mm) * DIM_ + k0 + kk];
      a_lds[kk + 0][mm] = av.x; a_lds[kk + 1][mm] = av.y;
      a_lds[kk + 2][mm] = av.z; a_lds[kk + 3][mm] = av.w;
    }
    {
      int nn = tid >> 2, kk = (tid & 3) << 2;
      int gn = n0 + nn;
      float4 v1 = make_float4(0.f, 0.f, 0.f, 0.f), v2 = v1;
      if (gn < HID_) {
        v1 = *(const float4*)&W[(size_t)gn * DIM_ + k0 + kk];
        v2 = *(const float4*)&W[(size_t)(gn + HID_) * DIM_ + k0 + kk];
      }
      w1_lds[kk + 0][nn] = v1.x; w1_lds[kk + 1][nn] = v1.y;
      w1_lds[kk + 2][nn] = v1.z; w1_lds[kk + 3][nn] = v1.w;
      w2_lds[kk + 0][nn] = v2.x; w2_lds[kk + 1][nn] = v2.y;
      w2_lds[kk + 2][nn] = v2.z; w2_lds[kk + 3][nn] = v2.w;
    }
    __syncthreads();
#pragma unroll
    for (int kk = 0; kk < 16; ++kk) {
      float4 a0 = *(const float4*)&a_lds[kk][tm * 8];
      float4 a1 = *(const float4*)&a_lds[kk][tm * 8 + 4];
      float4 w1 = *(const float4*)&w1_lds[kk][tn * 4];
      float4 w2 = *(const float4*)&w2_lds[kk][tn * 4];
      float av[8] = {a0.x, a0.y, a0.z, a0.w, a1.x, a1.y, a1.z, a1.w};
      float wv1[4] = {w1.x, w1.y, w1.z, w1.w};
      float wv2[4] = {w2.x, w2.y, w2.z, w2.w};
#pragma unroll
      for (int i = 0; i < 8; ++i)
#pragma unroll
        for (int j = 0; j < 4; ++j) {
          acc1[i][j] = fmaf(av[i], wv1[j], acc1[i][j]);
          acc2[i][j] = fmaf(av[i], wv2[j], acc2[i][j]);
        }
    }
  }
#pragma unroll
  for (int i = 0; i < 8; ++i) {
    int m = m0 + tm * 8 + i;
#pragma unroll
    for (int j = 0; j < 4; ++j) {
      int n = n0 + tn * 4 + j;
      if (n < GLD_) {
        float x1 = acc1[i][j], x2 = acc2[i][j];
        float val = (x1 / (1.f + __expf(-x1))) * x2;
        G[(size_t)m * GLD_ + n] = (n < HID_) ? val : 0.f;
      }
    }
  }
}

// ---------------- RoPE in-place on q,k slots of qkv ----------------
extern "C" __global__ __launch_bounds__(256)
void k_rope(float* __restrict__ qkv, const float* __restrict__ fc) {
  int idx = blockIdx.x * 256 + threadIdx.x;
  int i = idx & 31;
  int h = (idx >> 5) & 15;
  int s = (idx >> 9) & 1;
  int l = (idx >> 10) & 1023;
  int b = idx >> 20;
  float2 f = ((const float2*)fc)[l * 32 + i];
  float2* p = (float2*)(qkv + ((size_t)((b * LEN_ + l) * 3 + s)) * DIM_ + h * DH_ + 2 * i);
  float2 v = *p;
  *p = make_float2(v.x * f.x - v.y * f.y, v.y * f.x + v.x * f.y);
}

// ---------------- flash attention 1 (full softmax) ----------------
#define A1_RW 8
extern "C" __global__ __launch_bounds__(256)
void k_attn1(const float* __restrict__ qkv, float* __restrict__ o) {
  __shared__ float k_lds[64][68];        // [key][d]
  __shared__ float v_lds[64][68];        // [d][key] (transposed)
  __shared__ float q_lds[4][A1_RW][64];
  __shared__ float p_lds[4][64];
  int b = blockIdx.y >> 4, h = blockIdx.y & 15;
  int wave = threadIdx.x >> 6, lane = threadIdx.x & 63;
  int l0 = blockIdx.x * (4 * A1_RW) + wave * A1_RW;
  const float scale = 0.125f;
#pragma unroll
  for (int r = 0; r < A1_RW; ++r)
    q_lds[wave][r][lane] =
        qkv[((size_t)((b * LEN_ + l0 + r) * 3 + 0)) * DIM_ + h * DH_ + lane] * scale;
  float oacc[A1_RW], mrow[A1_RW], ssum[A1_RW];
#pragma unroll
  for (int r = 0; r < A1_RW; ++r) { oacc[r] = 0.f; mrow[r] = -1e30f; ssum[r] = 0.f; }

  for (int t = 0; t < 16; ++t) {
    __syncthreads();
    for (int idx = threadIdx.x; idx < 64 * 16; idx += 256) {
      int row = idx >> 4, d4 = (idx & 15) << 2;
      const float* base = qkv + ((size_t)((b * LEN_ + t * 64 + row) * 3 + 1)) * DIM_ + h * DH_ + d4;
      float4 kv = *(const float4*)base;
      float4 vv = *(const float4*)(base + DIM_);
      *(float4*)&k_lds[row][d4] = kv;
      v_lds[d4 + 0][row] = vv.x; v_lds[d4 + 1][row] = vv.y;
      v_lds[d4 + 2][row] = vv.z; v_lds[d4 + 3][row] = vv.w;
    }
    __syncthreads();
#pragma unroll
    for (int r = 0; r < A1_RW; ++r) {
      float s = 0.f;
#pragma unroll
      for (int i4 = 0; i4 < 16; ++i4) {
        float4 kv = *(const float4*)&k_lds[lane][i4 << 2];
        s = fmaf(q_lds[wave][r][i4 * 4 + 0], kv.x, s);
        s = fmaf(q_lds[wave][r][i4 * 4 + 1], kv.y, s);
        s = fmaf(q_lds[wave][r][i4 * 4 + 2], kv.z, s);
        s = fmaf(q_lds[wave][r][i4 * 4 + 3], kv.w, s);
      }
      float mx = wave_max(s);
      float mnew = fmaxf(mrow[r], mx);
      float p = __expf(s - mnew);
      float ps = wave_sum(p);
      float corr = __expf(mrow[r] - mnew);
      mrow[r] = mnew;
      ssum[r] = ssum[r] * corr + ps;
      p_lds[wave][lane] = p;            // wave-synchronous LDS (same wave RAW)
      float acc = 0.f;
#pragma unroll
      for (int j4 = 0; j4 < 16; ++j4) {
        float4 vv = *(const float4*)&v_lds[lane][j4 << 2];
        acc = fmaf(p_lds[wave][j4 * 4 + 0], vv.x, acc);
        acc = fmaf(p_lds[wave][j4 * 4 + 1], vv.y, acc);
        acc = fmaf(p_lds[wave][j4 * 4 + 2], vv.z, acc);
        acc = fmaf(p_lds[wave][j4 * 4 + 3], vv.w, acc);
      }
      oacc[r] = oacc[r] * corr + acc;
    }
  }
#pragma unroll
  for (int r = 0; r < A1_RW; ++r)
    o[((size_t)(b * LEN_ + l0 + r)) * DIM_ + h * DH_ + lane] = oacc[r] / ssum[r];
}

// ---------------- attention 2 with exact top-k softmax ----------------
#define A2_RW 8
extern "C" __global__ __launch_bounds__(256)
void k_attn2(const float* __restrict__ q2, const float* __restrict__ k2,
             const float* __restrict__ styles, const int* __restrict__ topk_p,
             float* __restrict__ out) {
  __shared__ float k_lds[64][68];
  __shared__ float q_lds[4][A2_RW][64];
  int b = blockIdx.y >> 4, h = blockIdx.y & 15;
  int wave = threadIdx.x >> 6, lane = threadIdx.x & 63;
  int l0 = blockIdx.x * (4 * A2_RW) + wave * A2_RW;
  int topk = *topk_p;
  const float scale = 0.125f;
#pragma unroll
  for (int r = 0; r < A2_RW; ++r)
    q_lds[wave][r][lane] = q2[((size_t)(b * LEN_ + l0 + r)) * DIM_ + h * DH_ + lane] * scale;

  float sc[A2_RW][8];
#pragma unroll
  for (int t = 0; t < 8; ++t) {
    __syncthreads();
    for (int idx = threadIdx.x; idx < 64 * 16; idx += 256) {
      int row = idx >> 4, d4 = (idx & 15) << 2;
      *(float4*)&k_lds[row][d4] =
          *(const float4*)(k2 + ((size_t)(b * SLEN_ + t * 64 + row)) * DIM_ + h * DH_ + d4);
    }
    __syncthreads();
#pragma unroll
    for (int r = 0; r < A2_RW; ++r) {
      float s = 0.f;
#pragma unroll
      for (int i4 = 0; i4 < 16; ++i4) {
        float4 kv = *(const float4*)&k_lds[lane][i4 << 2];
        s = fmaf(q_lds[wave][r][i4 * 4 + 0], kv.x, s);
        s = fmaf(q_lds[wave][r][i4 * 4 + 1], kv.y, s);
        s = fmaf(q_lds[wave][r][i4 * 4 + 2], kv.z, s);
        s = fmaf(q_lds[wave][r][i4 * 4 + 3], kv.w, s);
      }
      sc[r][t] = s;
    }
  }
#pragma unroll
  for (int r = 0; r < A2_RW; ++r) {
    float sc2[8];
#pragma unroll
    for (int t = 0; t < 8; ++t) sc2[t] = sc[r][t];
    float gmax = -1e30f, cutoff = -1e30f;
    for (int kk = 0; kk < topk; ++kk) {
      float local = sc2[0];
#pragma unroll
      for (int t = 1; t < 8; ++t) local = fmaxf(local, sc2[t]);
      float wm = wave_max(local);
      if (kk == 0) gmax = wm;
      cutoff = wm;
      unsigned long long msk = __ballot(local == wm);
      int firstl = __ffsll(msk) - 1;
      if (lane == firstl) {
        bool done = false;
#pragma unroll
        for (int t = 0; t < 8; ++t) {
          if (!done && sc2[t] == wm) { sc2[t] = -1e30f; done = true; }
        }
      }
    }
    float p[8];
    float psum = 0.f;
#pragma unroll
    for (int t = 0; t < 8; ++t) {
      p[t] = (sc[r][t] >= cutoff) ? __expf(sc[r][t] - gmax) : 0.f;
      psum += p[t];
    }
    float denom = wave_sum(psum);
    float e = 0.f;
#pragma unroll
    for (int t = 0; t < 8; ++t) {
      unsigned long long m = __ballot(p[t] > 0.f);
      while (m) {
        int j = __ffsll(m) - 1;
        m &= m - 1;
        float wgt = __shfl(p[t], j);
        e = fmaf(wgt, styles[((size_t)(b * SLEN_ + t * 64 + j)) * DIM_ + h * DH_ + lane], e);
      }
    }
    out[((size_t)(b * LEN_ + l0 + r)) * DIM_ + h * DH_ + lane] = e / denom;
  }
}

// ---------------- launcher ----------------
extern "C" void kernel_launch(void* const* d_in, const int* in_sizes, int n_in,
                              void* d_out, int out_size, void* d_ws, size_t ws_size,
                              hipStream_t stream) {
  const float* x       = (const float*)d_in[0];
  const float* styles  = (const float*)d_in[1];
  const float* fc      = (const float*)d_in[2];
  const float* gn1_w   = (const float*)d_in[3];
  const float* gn1_b   = (const float*)d_in[4];
  const float* conv1_w = (const float*)d_in[5];
  const float* conv1_b = (const float*)d_in[6];
  const float* gn2_w   = (const float*)d_in[7];
  const float* gn2_b   = (const float*)d_in[8];
  const float* conv2_w = (const float*)d_in[9];
  const float* conv2_b = (const float*)d_in[10];
  const float* skip_w  = (const float*)d_in[11];
  const float* skip_b  = (const float*)d_in[12];
  const float* norm1_w = (const float*)d_in[13];
  const float* qkv_w   = (const float*)d_in[14];
  const float* proj_w  = (const float*)d_in[15];
  const float* proj_b  = (const float*)d_in[16];
  const float* norm2_w = (const float*)d_in[17];
  const float* w12_w   = (const float*)d_in[18];
  const float* w3_w    = (const float*)d_in[19];
  const float* q_w     = (const float*)d_in[20];
  const float* k_w     = (const float*)d_in[21];
  const int*   topk    = (const int*)d_in[22];
  float* out = (float*)d_out;

  char* ws = (char*)d_ws;
  const size_t OFF_A1 = 1ull << 20;
  const size_t OFF_R2 = 2ull << 20;
  const size_t OFF_R3 = OFF_R2 + (16ull << 20);
  const size_t OFF_R4 = OFF_R3 + (16ull << 20);
  const size_t OFF_R5 = OFF_R4 + (16ull << 20);
  const size_t NEED = OFF_R5 + (48ull << 20);   // 98 MB
  if (ws_size < NEED) return;  // loud failure: output stays poisoned

  float2* part = (float2*)ws;
  float2* mr   = (float2*)(ws + (32 << 10));
  float* a1 = (float*)(ws + OFF_A1);  // silu(gn1(x)) : (B,CIN,L)
  float* r2 = (float*)(ws + OFF_R2);  // h1 / h2 / o / q2
  float* r3 = (float*)(ws + OFF_R3);  // a2 / n / m / k2
  float* t  = (float*)(ws + OFF_R4);  // residual stream (B,L,D)
  float* r5 = (float*)(ws + OFF_R5);  // qkv (48MB) / g (padded, 44.9MB)
  float* w3p = out;                   // padded w3 weight (11.2MB), scratch in d_out;
                                      // fully overwritten by k_attn2 at the end.

  // w3 weight repack (padded K) -> d_out scratch
  k_padcopy_w3<<<(1024 * GLD_) / 256, 256, 0, stream>>>(w3_w, w3p);
  // GN1 + silu
  k_partial_stats<<<dim3(64, B_), 256, 0, stream>>>(x, part, CIN_ * LEN_);
  k_finalize_stats<<<B_, 64, 0, stream>>>(part, mr, 1.f / (CIN_ * LEN_), 1e-5f);
  k_gn_silu<<<B_ * CIN_ * LEN_ / 1024, 256, 0, stream>>>(x, mr, gn1_w, gn1_b, a1, 6, B_ * CIN_ * LEN_ / 4);
  // conv1 -> h1 (r2)
  k_conv1d_k3<<<dim3(16, 16, B_), 256, 0, stream>>>(a1, conv1_w, conv1_b, r2, CIN_, DIM_);
  // GN2 + silu -> a2 (r3)
  k_partial_stats<<<dim3(64, B_), 256, 0, stream>>>(r2, part, DIM_ * LEN_);
  k_finalize_stats<<<B_, 64, 0, stream>>>(part, mr, 1.f / (DIM_ * LEN_), 1e-5f);
  k_gn_silu<<<B_ * DIM_ * LEN_ / 1024, 256, 0, stream>>>(r2, mr, gn2_w, gn2_b, r3, 10, B_ * DIM_ * LEN_ / 4);
  // conv2 -> h2 (r2)
  k_conv1d_k3<<<dim3(16, 16, B_), 256, 0, stream>>>(r3, conv2_w, conv2_b, r2, DIM_, DIM_);
  // xp = h2 + skipconv(x), transposed -> t (B,L,D)
  k_add_skip<<<dim3(16, 16, B_), 256, 0, stream>>>(x, skip_w, skip_b, r2, t);
  // rmsnorm1 -> n (r3)
  k_rmsnorm<<<B_ * LEN_, 256, 0, stream>>>(t, norm1_w, r3);
  // qkv = n @ qkv_w^T -> r5   (M=4096, N=3072, K=1024)
  k_sgemm<<<dim3(24, 32), 256, 0, stream>>>(r3, DIM_, qkv_w, DIM_, nullptr, nullptr,
                                            r5, 3 * DIM_, DIM_);
  // rope on q,k
  k_rope<<<16384, 256, 0, stream>>>(r5, fc);
  // attention1 -> o (r2)
  k_attn1<<<dim3(LEN_ / 32, B_ * NH_), 256, 0, stream>>>(r5, r2);
  // t = t + o @ proj_w^T + proj_b (in-place; each block touches only its own tile)
  k_sgemm<<<dim3(8, 32), 256, 0, stream>>>(r2, DIM_, proj_w, DIM_, t, proj_b,
                                           t, DIM_, DIM_);
  // rmsnorm2 -> m (r3)
  k_rmsnorm<<<B_ * LEN_, 256, 0, stream>>>(t, norm2_w, r3);
  // g = silu(m@W1^T)*(m@W2^T) -> r5 (rows padded/zero-filled to GLD_)
  k_glu_gemm<<<dim3((GLD_ + 63) / 64, 32), 256, 0, stream>>>(r3, w12_w, r5);
  // t = t + g @ w3p^T (in-place; padded K, zero tails on both operands)
  k_sgemm<<<dim3(8, 32), 256, 0, stream>>>(r5, GLD_, w3p, GLD_, t, nullptr,
                                           t, DIM_, GLD_);
  // q2 = t @ q_w^T -> r2
  k_sgemm<<<dim3(8, 32), 256, 0, stream>>>(t, DIM_, q_w, DIM_, nullptr, nullptr,
                                           r2, DIM_, DIM_);
  // k2 = styles @ k_w^T -> r3  (M=2048)
  k_sgemm<<<dim3(8, 16), 256, 0, stream>>>(styles, DIM_, k_w, DIM_, nullptr, nullptr,
                                           r3, DIM_, DIM_);
  // attention2 (top-k softmax) -> out (overwrites w3p scratch completely)
  k_attn2<<<dim3(LEN_ / 32, B_ * NH_), 256, 0, stream>>>(r2, r3, styles, topk, out);
}

// Round 6
// 5388.375 us; speedup vs baseline: 1.1156x; 1.1156x over previous
//
#include <hip/hip_runtime.h>

#define B_    4
#define CIN_  64
#define LEN_  1024
#define DIM_  1024
#define NH_   16
#define DH_   64
#define SLEN_ 512
#define HID_  2730
#define GLD_  2736   // K padded to multiple of 16; zero-filled tail

__device__ __forceinline__ float wave_sum(float v) {
#pragma unroll
  for (int off = 32; off; off >>= 1) v += __shfl_xor(v, off);
  return v;
}
__device__ __forceinline__ float wave_max(float v) {
#pragma unroll
  for (int off = 32; off; off >>= 1) v = fmaxf(v, __shfl_xor(v, off));
  return v;
}

// ---------------- group-norm stats (two-stage, deterministic) ----------------
extern "C" __global__ __launch_bounds__(256)
void k_partial_stats(const float* __restrict__ x, float2* __restrict__ part, int perBatch) {
  int b = blockIdx.y, chunk = blockIdx.x;
  int chunkElems = perBatch >> 6;  // 64 chunks per batch
  const float4* p = (const float4*)(x + (size_t)b * perBatch + (size_t)chunk * chunkElems);
  int n4 = chunkElems >> 2;
  float s = 0.f, sq = 0.f;
  for (int i = threadIdx.x; i < n4; i += 256) {
    float4 v = p[i];
    s += v.x + v.y + v.z + v.w;
    sq += v.x * v.x + v.y * v.y + v.z * v.z + v.w * v.w;
  }
  s = wave_sum(s); sq = wave_sum(sq);
  __shared__ float red[8];
  int w = threadIdx.x >> 6;
  if ((threadIdx.x & 63) == 0) { red[w] = s; red[4 + w] = sq; }
  __syncthreads();
  if (threadIdx.x == 0) {
    part[b * 64 + chunk] = make_float2(red[0] + red[1] + red[2] + red[3],
                                       red[4] + red[5] + red[6] + red[7]);
  }
}

extern "C" __global__ __launch_bounds__(64)
void k_finalize_stats(const float2* __restrict__ part, float2* __restrict__ mr,
                      float invN, float eps) {
  int b = blockIdx.x;
  float2 v = part[b * 64 + threadIdx.x];
  float s = wave_sum(v.x), sq = wave_sum(v.y);
  if (threadIdx.x == 0) {
    float mean = s * invN;
    float var = sq * invN - mean * mean;
    mr[b] = make_float2(mean, rsqrtf(var + eps));
  }
}

// ---------------- groupnorm-apply + silu (elementwise) ----------------
extern "C" __global__ __launch_bounds__(256)
void k_gn_silu(const float* __restrict__ x, const float2* __restrict__ mr,
               const float* __restrict__ w, const float* __restrict__ bias,
               float* __restrict__ y, int cshift, int total4) {
  int idx = blockIdx.x * 256 + threadIdx.x;
  if (idx >= total4) return;
  int cl = idx >> 8;                       // (idx*4)/1024 = row index (b*C + c)
  int c = cl & ((1 << cshift) - 1);
  int b = cl >> cshift;
  float2 m = mr[b];
  float wc = w[c] * m.y;
  float bc = bias[c] - m.x * m.y * w[c];
  float4 v = ((const float4*)x)[idx];
  float4 o;
  float t;
  t = v.x * wc + bc; o.x = t / (1.f + __expf(-t));
  t = v.y * wc + bc; o.y = t / (1.f + __expf(-t));
  t = v.z * wc + bc; o.z = t / (1.f + __expf(-t));
  t = v.w * wc + bc; o.w = t / (1.f + __expf(-t));
  ((float4*)y)[idx] = o;
}

// ---------------- conv1d k=3 pad=1 (tiled) ----------------
extern "C" __global__ __launch_bounds__(256)
void k_conv1d_k3(const float* __restrict__ in, const float* __restrict__ w,
                 const float* __restrict__ bias, float* __restrict__ out,
                 int Cin, int Cout) {
  __shared__ float in_lds[16][66];
  __shared__ float w_lds[64][49];
  int b = blockIdx.z;
  int d0 = blockIdx.y * 64;
  int l0 = blockIdx.x * 64;
  int tid = threadIdx.x;
  int tc = tid & 15, tr = tid >> 4;
  float acc[4][4] = {{0.f}};
  for (int c0 = 0; c0 < Cin; c0 += 16) {
    __syncthreads();
    for (int idx = tid; idx < 16 * 66; idx += 256) {
      int cc = idx / 66, ll = idx % 66;
      int gl = l0 + ll - 1;
      float v = 0.f;
      if (gl >= 0 && gl < LEN_) v = in[((size_t)b * Cin + (c0 + cc)) * LEN_ + gl];
      in_lds[cc][ll] = v;
    }
    for (int idx = tid; idx < 64 * 48; idx += 256) {
      int dd = idx / 48, r = idx % 48;
      w_lds[dd][r] = w[((size_t)(d0 + dd) * Cin + c0) * 3 + r];
    }
    __syncthreads();
#pragma unroll 4
    for (int cc = 0; cc < 16; ++cc) {
      float iv[6];
#pragma unroll
      for (int u = 0; u < 6; ++u) iv[u] = in_lds[cc][tc * 4 + u];
      float wv[4][3];
#pragma unroll
      for (int i = 0; i < 4; ++i)
#pragma unroll
        for (int k = 0; k < 3; ++k) wv[i][k] = w_lds[tr * 4 + i][cc * 3 + k];
#pragma unroll
      for (int i = 0; i < 4; ++i)
#pragma unroll
        for (int j = 0; j < 4; ++j)
#pragma unroll
          for (int k = 0; k < 3; ++k)
            acc[i][j] = fmaf(wv[i][k], iv[j + k], acc[i][j]);
    }
  }
#pragma unroll
  for (int i = 0; i < 4; ++i) {
    int d = d0 + tr * 4 + i;
    float bs = bias[d];
    float4 res = make_float4(acc[i][0] + bs, acc[i][1] + bs, acc[i][2] + bs, acc[i][3] + bs);
    *(float4*)&out[((size_t)b * Cout + d) * LEN_ + l0 + tc * 4] = res;
  }
}

// ---------------- skip-conv (k=1) + add + transpose -> t[b,l,d] ----------------
extern "C" __global__ __launch_bounds__(256)
void k_add_skip(const float* __restrict__ x, const float* __restrict__ sw,
                const float* __restrict__ sb, const float* __restrict__ h2,
                float* __restrict__ t) {
  __shared__ float x_lds[64][65];   // [c][l_local]
  __shared__ float w_lds[64][65];   // [d_local][c]
  __shared__ float h_lds[64][68];   // [l_local][d_local]
  int b = blockIdx.z;
  int d0 = blockIdx.y * 64;
  int l0 = blockIdx.x * 64;
  int tid = threadIdx.x;
  int tn = tid & 15, tm = tid >> 4;
  for (int idx = tid; idx < 4096; idx += 256) {
    int r = idx >> 6, q = idx & 63;
    x_lds[r][q] = x[((size_t)b * CIN_ + r) * LEN_ + l0 + q];
    w_lds[r][q] = sw[(size_t)(d0 + r) * CIN_ + q];
    h_lds[q][r] = h2[((size_t)b * DIM_ + d0 + r) * LEN_ + l0 + q];
  }
  __syncthreads();
  float acc[4][4] = {{0.f}};
#pragma unroll 8
  for (int c = 0; c < 64; ++c) {
    float xv[4], wv[4];
#pragma unroll
    for (int il = 0; il < 4; ++il) xv[il] = x_lds[c][tm * 4 + il];
#pragma unroll
    for (int jd = 0; jd < 4; ++jd) wv[jd] = w_lds[tn * 4 + jd][c];
#pragma unroll
    for (int il = 0; il < 4; ++il)
#pragma unroll
      for (int jd = 0; jd < 4; ++jd)
        acc[il][jd] = fmaf(xv[il], wv[jd], acc[il][jd]);
  }
  float4 bb = *(const float4*)&sb[d0 + tn * 4];
#pragma unroll
  for (int il = 0; il < 4; ++il) {
    int l = l0 + tm * 4 + il;
    float4 hv = *(const float4*)&h_lds[tm * 4 + il][tn * 4];
    float4 res = make_float4(acc[il][0] + hv.x + bb.x, acc[il][1] + hv.y + bb.y,
                             acc[il][2] + hv.z + bb.z, acc[il][3] + hv.w + bb.w);
    *(float4*)&t[((size_t)(b * LEN_ + l)) * DIM_ + d0 + tn * 4] = res;
  }
}

// ---------------- rmsnorm over last dim (1024) ----------------
extern "C" __global__ __launch_bounds__(256)
void k_rmsnorm(const float* __restrict__ x, const float* __restrict__ w,
               float* __restrict__ y) {
  size_t row = blockIdx.x;
  const float4* xr = (const float4*)(x + row * DIM_);
  float4 v = xr[threadIdx.x];
  float ss = v.x * v.x + v.y * v.y + v.z * v.z + v.w * v.w;
  ss = wave_sum(ss);
  __shared__ float red[4];
  if ((threadIdx.x & 63) == 0) red[threadIdx.x >> 6] = ss;
  __syncthreads();
  float tot = red[0] + red[1] + red[2] + red[3];
  float rs = rsqrtf(tot * (1.f / DIM_) + 1e-6f);
  float4 wv = ((const float4*)w)[threadIdx.x];
  float4 o = make_float4(v.x * rs * wv.x, v.y * rs * wv.y, v.z * rs * wv.z, v.w * rs * wv.w);
  ((float4*)(y + row * DIM_))[threadIdx.x] = o;
}

// ---------------- pad-repack w3_w [1024][2730] -> [1024][2736] (zero tail) ----
extern "C" __global__ __launch_bounds__(256)
void k_padcopy_w3(const float* __restrict__ src, float* __restrict__ dst) {
  int idx = blockIdx.x * 256 + threadIdx.x;   // over 1024*2736, exact grid
  int n = idx / GLD_;
  int k = idx - n * GLD_;
  dst[idx] = (k < HID_) ? src[(size_t)n * HID_ + k] : 0.f;
}

// ------- generic fp32 GEMM: C[M,N] = A[M,K] * W[N,K]^T (+add)(+bias) --------
// REQUIRES: M%128==0 (grid.y=M/128), N%128==0 (grid.x=N/128), K%16==0,
//           lda%4==0, ldw%4==0. No bounds checks.
extern "C" __global__ __launch_bounds__(256)
void k_sgemm(const float* __restrict__ A, int lda,
             const float* __restrict__ W, int ldw,
             const float* __restrict__ addsrc, const float* __restrict__ bias,
             float* __restrict__ C, int ldc,
             int K) {
  __shared__ float a_lds[16][132];
  __shared__ float w_lds[16][132];
  int n0 = blockIdx.x * 128;
  int m0 = blockIdx.y * 128;
  int tid = threadIdx.x;
  int tn = tid & 15, tm = tid >> 4;
  float acc[8][8] = {{0.f}};
  for (int k0 = 0; k0 < K; k0 += 16) {
    __syncthreads();
#pragma unroll
    for (int q = 0; q < 2; ++q) {
      int s = tid * 2 + q;                 // 0..511
      int mm = s >> 2, kk = (s & 3) << 2;
      float4 av = *(const float4*)&A[(size_t)(m0 + mm) * lda + k0 + kk];
      a_lds[kk + 0][mm] = av.x; a_lds[kk + 1][mm] = av.y;
      a_lds[kk + 2][mm] = av.z; a_lds[kk + 3][mm] = av.w;
      float4 wv = *(const float4*)&W[(size_t)(n0 + mm) * ldw + k0 + kk];
      w_lds[kk + 0][mm] = wv.x; w_lds[kk + 1][mm] = wv.y;
      w_lds[kk + 2][mm] = wv.z; w_lds[kk + 3][mm] = wv.w;
    }
    __syncthreads();
#pragma unroll
    for (int kk = 0; kk < 16; ++kk) {
      float4 a0 = *(const float4*)&a_lds[kk][tm * 8];
      float4 a1 = *(const float4*)&a_lds[kk][tm * 8 + 4];
      float4 w0 = *(const float4*)&w_lds[kk][tn * 8];
      float4 w1 = *(const float4*)&w_lds[kk][tn * 8 + 4];
      float av[8] = {a0.x, a0.y, a0.z, a0.w, a1.x, a1.y, a1.z, a1.w};
      float wv[8] = {w0.x, w0.y, w0.z, w0.w, w1.x, w1.y, w1.z, w1.w};
#pragma unroll
      for (int i = 0; i < 8; ++i)
#pragma unroll
        for (int j = 0; j < 8; ++j)
          acc[i][j] = fmaf(av[i], wv[j], acc[i][j]);
    }
  }
#pragma unroll
  for (int i = 0; i < 8; ++i) {
    int m = m0 + tm * 8 + i;
    int n = n0 + tn * 8;
    size_t off = (size_t)m * ldc + n;
    float4 r0 = make_float4(acc[i][0], acc[i][1], acc[i][2], acc[i][3]);
    float4 r1 = make_float4(acc[i][4], acc[i][5], acc[i][6], acc[i][7]);
    if (bias) {
      float4 b0 = *(const float4*)&bias[n];
      float4 b1 = *(const float4*)&bias[n + 4];
      r0.x += b0.x; r0.y += b0.y; r0.z += b0.z; r0.w += b0.w;
      r1.x += b1.x; r1.y += b1.y; r1.z += b1.z; r1.w += b1.w;
    }
    if (addsrc) {
      float4 s0 = *(const float4*)&addsrc[off];
      float4 s1 = *(const float4*)&addsrc[off + 4];
      r0.x += s0.x; r0.y += s0.y; r0.z += s0.z; r0.w += s0.w;
      r1.x += s1.x; r1.y += s1.y; r1.z += s1.z; r1.w += s1.w;
    }
    *(float4*)&C[off] = r0;
    *(float4*)&C[off + 4] = r1;
  }
}

// ---------------- fused GLU GEMM: g = silu(A*W1^T) * (A*W2^T) ----------------
// writes zero into pad columns [HID_, GLD_)
extern "C" __global__ __launch_bounds__(256)
void k_glu_gemm(const float* __restrict__ A, const float* __restrict__ W,
                float* __restrict__ G) {
  __shared__ float a_lds[16][132];
  __shared__ float w1_lds[16][68];
  __shared__ float w2_lds[16][68];
  int n0 = blockIdx.x * 64;
  int m0 = blockIdx.y * 128;
  int tid = threadIdx.x;
  int tn = tid & 15, tm = tid >> 4;
  float acc1[8][4] = {{0.f}}, acc2[8][4] = {{0.f}};
  for (int k0 = 0; k0 < DIM_; k0 += 16) {
    __syncthreads();
#pragma unroll
    for (int q = 0; q < 2; ++q) {
      int s = tid * 2 + q;
      int mm = s >> 2, kk = (s & 3) << 2;
      float4 av = *(const float4*)&A[(size_t)(m0 + mm) * DIM_ + k0 + kk];
      a_lds[kk + 0][mm] = av.x; a_lds[kk + 1][mm] = av.y;
      a_lds[kk + 2][mm] = av.z; a_lds[kk + 3][mm] = av.w;
    }
    {
      int nn = tid >> 2, kk = (tid & 3) << 2;
      int gn = n0 + nn;
      float4 v1 = make_float4(0.f, 0.f, 0.f, 0.f), v2 = v1;
      if (gn < HID_) {
        v1 = *(const float4*)&W[(size_t)gn * DIM_ + k0 + kk];
        v2 = *(const float4*)&W[(size_t)(gn + HID_) * DIM_ + k0 + kk];
      }
      w1_lds[kk + 0][nn] = v1.x; w1_lds[kk + 1][nn] = v1.y;
      w1_lds[kk + 2][nn] = v1.z; w1_lds[kk + 3][nn] = v1.w;
      w2_lds[kk + 0][nn] = v2.x; w2_lds[kk + 1][nn] = v2.y;
      w2_lds[kk + 2][nn] = v2.z; w2_lds[kk + 3][nn] = v2.w;
    }
    __syncthreads();
#pragma unroll
    for (int kk = 0; kk < 16; ++kk) {
      float4 a0 = *(const float4*)&a_lds[kk][tm * 8];
      float4 a1 = *(const float4*)&a_lds[kk][tm * 8 + 4];
      float4 w1 = *(const float4*)&w1_lds[kk][tn * 4];
      float4 w2 = *(const float4*)&w2_lds[kk][tn * 4];
      float av[8] = {a0.x, a0.y, a0.z, a0.w, a1.x, a1.y, a1.z, a1.w};
      float wv1[4] = {w1.x, w1.y, w1.z, w1.w};
      float wv2[4] = {w2.x, w2.y, w2.z, w2.w};
#pragma unroll
      for (int i = 0; i < 8; ++i)
#pragma unroll
        for (int j = 0; j < 4; ++j) {
          acc1[i][j] = fmaf(av[i], wv1[j], acc1[i][j]);
          acc2[i][j] = fmaf(av[i], wv2[j], acc2[i][j]);
        }
    }
  }
#pragma unroll
  for (int i = 0; i < 8; ++i) {
    int m = m0 + tm * 8 + i;
#pragma unroll
    for (int j = 0; j < 4; ++j) {
      int n = n0 + tn * 4 + j;
      if (n < GLD_) {
        float x1 = acc1[i][j], x2 = acc2[i][j];
        float val = (x1 / (1.f + __expf(-x1))) * x2;
        G[(size_t)m * GLD_ + n] = (n < HID_) ? val : 0.f;
      }
    }
  }
}

// ---------------- RoPE in-place on q,k slots of qkv ----------------
extern "C" __global__ __launch_bounds__(256)
void k_rope(float* __restrict__ qkv, const float* __restrict__ fc) {
  int idx = blockIdx.x * 256 + threadIdx.x;
  int i = idx & 31;
  int h = (idx >> 5) & 15;
  int s = (idx >> 9) & 1;
  int l = (idx >> 10) & 1023;
  int b = idx >> 20;
  float2 f = ((const float2*)fc)[l * 32 + i];
  float2* p = (float2*)(qkv + ((size_t)((b * LEN_ + l) * 3 + s)) * DIM_ + h * DH_ + 2 * i);
  float2 v = *p;
  *p = make_float2(v.x * f.x - v.y * f.y, v.y * f.x + v.x * f.y);
}

// ---------------- flash attention 1 (full softmax, fp32) ----------------
// Bit-exact arithmetic replay of the round-2-passing kernel (per-row op
// sequence unchanged: d-ascending QK chain, 64-lane butterfly max/sum,
// key-ascending PV chain, oacc = oacc*corr + acc). Order-preserving perf
// changes only: 4 rows/wave (was 8) -> 2x blocks & lower VGPR; V kept
// row-major [key][d] (kills the 8-way-conflicted transpose stores; PV reads
// v_lds[k][lane] = bank lane%32, conflict-free); q/p reads vectorized to
// float4 broadcasts (same values, same fmaf order).
#define A1_RW 4
extern "C" __global__ __launch_bounds__(256)
void k_attn1(const float* __restrict__ qkv, float* __restrict__ o) {
  __shared__ float k_lds[64][68];        // [key][d]
  __shared__ float v_lds[64][68];        // [key][d] (row-major!)
  __shared__ float q_lds[4][A1_RW][64];
  __shared__ float p_lds[4][64];
  int b = blockIdx.y >> 4, h = blockIdx.y & 15;
  int wave = threadIdx.x >> 6, lane = threadIdx.x & 63;
  int l0 = blockIdx.x * (4 * A1_RW) + wave * A1_RW;
  const float scale = 0.125f;
#pragma unroll
  for (int r = 0; r < A1_RW; ++r)
    q_lds[wave][r][lane] =
        qkv[((size_t)((b * LEN_ + l0 + r) * 3 + 0)) * DIM_ + h * DH_ + lane] * scale;
  float oacc[A1_RW], mrow[A1_RW], ssum[A1_RW];
#pragma unroll
  for (int r = 0; r < A1_RW; ++r) { oacc[r] = 0.f; mrow[r] = -1e30f; ssum[r] = 0.f; }

  for (int t = 0; t < 16; ++t) {
    __syncthreads();
    for (int idx = threadIdx.x; idx < 64 * 16; idx += 256) {
      int row = idx >> 4, d4 = (idx & 15) << 2;
      const float* base = qkv + ((size_t)((b * LEN_ + t * 64 + row) * 3 + 1)) * DIM_ + h * DH_ + d4;
      float4 kv = *(const float4*)base;
      float4 vv = *(const float4*)(base + DIM_);
      *(float4*)&k_lds[row][d4] = kv;
      *(float4*)&v_lds[row][d4] = vv;
    }
    __syncthreads();
#pragma unroll
    for (int r = 0; r < A1_RW; ++r) {
      float s = 0.f;
#pragma unroll
      for (int i4 = 0; i4 < 16; ++i4) {
        float4 kv = *(const float4*)&k_lds[lane][i4 << 2];
        float4 qv = *(const float4*)&q_lds[wave][r][i4 << 2];  // broadcast
        s = fmaf(qv.x, kv.x, s);
        s = fmaf(qv.y, kv.y, s);
        s = fmaf(qv.z, kv.z, s);
        s = fmaf(qv.w, kv.w, s);
      }
      float mx = wave_max(s);
      float mnew = fmaxf(mrow[r], mx);
      float p = __expf(s - mnew);
      float ps = wave_sum(p);
      float corr = __expf(mrow[r] - mnew);
      mrow[r] = mnew;
      ssum[r] = ssum[r] * corr + ps;
      p_lds[wave][lane] = p;            // wave-synchronous LDS (same wave RAW)
      float acc = 0.f;
#pragma unroll
      for (int j4 = 0; j4 < 16; ++j4) {
        float4 pv = *(const float4*)&p_lds[wave][j4 << 2];    // broadcast
        acc = fmaf(pv.x, v_lds[j4 * 4 + 0][lane], acc);
        acc = fmaf(pv.y, v_lds[j4 * 4 + 1][lane], acc);
        acc = fmaf(pv.z, v_lds[j4 * 4 + 2][lane], acc);
        acc = fmaf(pv.w, v_lds[j4 * 4 + 3][lane], acc);
      }
      oacc[r] = oacc[r] * corr + acc;
    }
  }
#pragma unroll
  for (int r = 0; r < A1_RW; ++r)
    o[((size_t)(b * LEN_ + l0 + r)) * DIM_ + h * DH_ + lane] = oacc[r] / ssum[r];
}

// ---------------- attention 2 with exact top-k softmax ----------------
#define A2_RW 8
extern "C" __global__ __launch_bounds__(256)
void k_attn2(const float* __restrict__ q2, const float* __restrict__ k2,
             const float* __restrict__ styles, const int* __restrict__ topk_p,
             float* __restrict__ out) {
  __shared__ float k_lds[64][68];
  __shared__ float q_lds[4][A2_RW][64];
  int b = blockIdx.y >> 4, h = blockIdx.y & 15;
  int wave = threadIdx.x >> 6, lane = threadIdx.x & 63;
  int l0 = blockIdx.x * (4 * A2_RW) + wave * A2_RW;
  int topk = *topk_p;
  const float scale = 0.125f;
#pragma unroll
  for (int r = 0; r < A2_RW; ++r)
    q_lds[wave][r][lane] = q2[((size_t)(b * LEN_ + l0 + r)) * DIM_ + h * DH_ + lane] * scale;

  float sc[A2_RW][8];
#pragma unroll
  for (int t = 0; t < 8; ++t) {
    __syncthreads();
    for (int idx = threadIdx.x; idx < 64 * 16; idx += 256) {
      int row = idx >> 4, d4 = (idx & 15) << 2;
      *(float4*)&k_lds[row][d4] =
          *(const float4*)(k2 + ((size_t)(b * SLEN_ + t * 64 + row)) * DIM_ + h * DH_ + d4);
    }
    __syncthreads();
#pragma unroll
    for (int r = 0; r < A2_RW; ++r) {
      float s = 0.f;
#pragma unroll
      for (int i4 = 0; i4 < 16; ++i4) {
        float4 kv = *(const float4*)&k_lds[lane][i4 << 2];
        s = fmaf(q_lds[wave][r][i4 * 4 + 0], kv.x, s);
        s = fmaf(q_lds[wave][r][i4 * 4 + 1], kv.y, s);
        s = fmaf(q_lds[wave][r][i4 * 4 + 2], kv.z, s);
        s = fmaf(q_lds[wave][r][i4 * 4 + 3], kv.w, s);
      }
      sc[r][t] = s;
    }
  }
#pragma unroll
  for (int r = 0; r < A2_RW; ++r) {
    float sc2[8];
#pragma unroll
    for (int t = 0; t < 8; ++t) sc2[t] = sc[r][t];
    float gmax = -1e30f, cutoff = -1e30f;
    for (int kk = 0; kk < topk; ++kk) {
      float local = sc2[0];
#pragma unroll
      for (int t = 1; t < 8; ++t) local = fmaxf(local, sc2[t]);
      float wm = wave_max(local);
      if (kk == 0) gmax = wm;
      cutoff = wm;
      unsigned long long msk = __ballot(local == wm);
      int firstl = __ffsll(msk) - 1;
      if (lane == firstl) {
        bool done = false;
#pragma unroll
        for (int t = 0; t < 8; ++t) {
          if (!done && sc2[t] == wm) { sc2[t] = -1e30f; done = true; }
        }
      }
    }
    float p[8];
    float psum = 0.f;
#pragma unroll
    for (int t = 0; t < 8; ++t) {
      p[t] = (sc[r][t] >= cutoff) ? __expf(sc[r][t] - gmax) : 0.f;
      psum += p[t];
    }
    float denom = wave_sum(psum);
    float e = 0.f;
#pragma unroll
    for (int t = 0; t < 8; ++t) {
      unsigned long long mm = __ballot(p[t] > 0.f);
      while (mm) {
        int j = __ffsll(mm) - 1;
        mm &= mm - 1;
        float wgt = __shfl(p[t], j);
        e = fmaf(wgt, styles[((size_t)(b * SLEN_ + t * 64 + j)) * DIM_ + h * DH_ + lane], e);
      }
    }
    out[((size_t)(b * LEN_ + l0 + r)) * DIM_ + h * DH_ + lane] = e / denom;
  }
}

// ---------------- launcher ----------------
extern "C" void kernel_launch(void* const* d_in, const int* in_sizes, int n_in,
                              void* d_out, int out_size, void* d_ws, size_t ws_size,
                              hipStream_t stream) {
  const float* x       = (const float*)d_in[0];
  const float* styles  = (const float*)d_in[1];
  const float* fc      = (const float*)d_in[2];
  const float* gn1_w   = (const float*)d_in[3];
  const float* gn1_b   = (const float*)d_in[4];
  const float* conv1_w = (const float*)d_in[5];
  const float* conv1_b = (const float*)d_in[6];
  const float* gn2_w   = (const float*)d_in[7];
  const float* gn2_b   = (const float*)d_in[8];
  const float* conv2_w = (const float*)d_in[9];
  const float* conv2_b = (const float*)d_in[10];
  const float* skip_w  = (const float*)d_in[11];
  const float* skip_b  = (const float*)d_in[12];
  const float* norm1_w = (const float*)d_in[13];
  const float* qkv_w   = (const float*)d_in[14];
  const float* proj_w  = (const float*)d_in[15];
  const float* proj_b  = (const float*)d_in[16];
  const float* norm2_w = (const float*)d_in[17];
  const float* w12_w   = (const float*)d_in[18];
  const float* w3_w    = (const float*)d_in[19];
  const float* q_w     = (const float*)d_in[20];
  const float* k_w     = (const float*)d_in[21];
  const int*   topk    = (const int*)d_in[22];
  float* out = (float*)d_out;

  char* ws = (char*)d_ws;
  const size_t OFF_A1 = 1ull << 20;
  const size_t OFF_R2 = 2ull << 20;
  const size_t OFF_R3 = OFF_R2 + (16ull << 20);
  const size_t OFF_R4 = OFF_R3 + (16ull << 20);
  const size_t OFF_R5 = OFF_R4 + (16ull << 20);
  const size_t NEED = OFF_R5 + (48ull << 20);   // 98 MB
  if (ws_size < NEED) return;  // loud failure: output stays poisoned

  float2* part = (float2*)ws;
  float2* mr   = (float2*)(ws + (32 << 10));
  float* a1 = (float*)(ws + OFF_A1);  // silu(gn1(x)) : (B,CIN,L)
  float* r2 = (float*)(ws + OFF_R2);  // h1 / h2 / o / q2
  float* r3 = (float*)(ws + OFF_R3);  // a2 / n / m / k2
  float* t  = (float*)(ws + OFF_R4);  // residual stream (B,L,D)
  float* r5 = (float*)(ws + OFF_R5);  // qkv (48MB) / g (padded, 44.9MB)
  float* w3p = out;                   // padded w3 weight (11.2MB), scratch in d_out;
                                      // fully overwritten by k_attn2 at the end.

  // w3 weight repack (padded K) -> d_out scratch
  k_padcopy_w3<<<(1024 * GLD_) / 256, 256, 0, stream>>>(w3_w, w3p);
  // GN1 + silu
  k_partial_stats<<<dim3(64, B_), 256, 0, stream>>>(x, part, CIN_ * LEN_);
  k_finalize_stats<<<B_, 64, 0, stream>>>(part, mr, 1.f / (CIN_ * LEN_), 1e-5f);
  k_gn_silu<<<B_ * CIN_ * LEN_ / 1024, 256, 0, stream>>>(x, mr, gn1_w, gn1_b, a1, 6, B_ * CIN_ * LEN_ / 4);
  // conv1 -> h1 (r2)
  k_conv1d_k3<<<dim3(16, 16, B_), 256, 0, stream>>>(a1, conv1_w, conv1_b, r2, CIN_, DIM_);
  // GN2 + silu -> a2 (r3)
  k_partial_stats<<<dim3(64, B_), 256, 0, stream>>>(r2, part, DIM_ * LEN_);
  k_finalize_stats<<<B_, 64, 0, stream>>>(part, mr, 1.f / (DIM_ * LEN_), 1e-5f);
  k_gn_silu<<<B_ * DIM_ * LEN_ / 1024, 256, 0, stream>>>(r2, mr, gn2_w, gn2_b, r3, 10, B_ * DIM_ * LEN_ / 4);
  // conv2 -> h2 (r2)
  k_conv1d_k3<<<dim3(16, 16, B_), 256, 0, stream>>>(r3, conv2_w, conv2_b, r2, DIM_, DIM_);
  // xp = h2 + skipconv(x), transposed -> t (B,L,D)
  k_add_skip<<<dim3(16, 16, B_), 256, 0, stream>>>(x, skip_w, skip_b, r2, t);
  // rmsnorm1 -> n (r3)
  k_rmsnorm<<<B_ * LEN_, 256, 0, stream>>>(t, norm1_w, r3);
  // qkv = n @ qkv_w^T -> r5   (M=4096, N=3072, K=1024)
  k_sgemm<<<dim3(24, 32), 256, 0, stream>>>(r3, DIM_, qkv_w, DIM_, nullptr, nullptr,
                                            r5, 3 * DIM_, DIM_);
  // rope on q,k
  k_rope<<<16384, 256, 0, stream>>>(r5, fc);
  // attention1 (fp32 flash, round-2 arithmetic, 4 rows/wave) -> o (r2)
  k_attn1<<<dim3(LEN_ / 16, B_ * NH_), 256, 0, stream>>>(r5, r2);
  // t = t + o @ proj_w^T + proj_b (in-place; each block touches only its own tile)
  k_sgemm<<<dim3(8, 32), 256, 0, stream>>>(r2, DIM_, proj_w, DIM_, t, proj_b,
                                           t, DIM_, DIM_);
  // rmsnorm2 -> m (r3)
  k_rmsnorm<<<B_ * LEN_, 256, 0, stream>>>(t, norm2_w, r3);
  // g = silu(m@W1^T)*(m@W2^T) -> r5 (rows padded/zero-filled to GLD_)
  k_glu_gemm<<<dim3((GLD_ + 63) / 64, 32), 256, 0, stream>>>(r3, w12_w, r5);
  // t = t + g @ w3p^T (in-place; padded K, zero tails on both operands)
  k_sgemm<<<dim3(8, 32), 256, 0, stream>>>(r5, GLD_, w3p, GLD_, t, nullptr,
                                           t, DIM_, GLD_);
  // q2 = t @ q_w^T -> r2
  k_sgemm<<<dim3(8, 32), 256, 0, stream>>>(t, DIM_, q_w, DIM_, nullptr, nullptr,
                                           r2, DIM_, DIM_);
  // k2 = styles @ k_w^T -> r3  (M=2048)
  k_sgemm<<<dim3(8, 16), 256, 0, stream>>>(styles, DIM_, k_w, DIM_, nullptr, nullptr,
                                           r3, DIM_, DIM_);
  // attention2 (top-k softmax) -> out (overwrites w3p scratch completely)
  k_attn2<<<dim3(LEN_ / 32, B_ * NH_), 256, 0, stream>>>(r2, r3, styles, topk, out);
}